// Round 2
// baseline (1603.267 us; speedup 1.0000x reference)
//
#include <hip/hip_runtime.h>
#include <hip/hip_bf16.h>

#define U 128
#define BATCH 2048
#define NL 8
#define NS 15
#define DTc 0.1f
#define TENf 10.0f                 /* DT/EPS */
#define INVC (1.0f/11.0f)          /* 1/(1+DT/EPS) */
#define AFACT (0.01f/11.0f)        /* DT^2 / c */

typedef unsigned short u16;

__device__ __forceinline__ float bf2f(u16 h){ return __uint_as_float(((unsigned int)h)<<16); }
__device__ __forceinline__ u16 f2bf(float f){
  unsigned int u = __float_as_uint(f);
  u += 0x7FFFu + ((u >> 16) & 1u);
  return (u16)(u >> 16);
}

// ---------------- dtype detect: bf16 interp of fp32 data has garbage exps ----
__global__ __launch_bounds__(256) void detectK(const u16* __restrict__ x, int* __restrict__ mode){
  __shared__ int bad;
  if(threadIdx.x == 0) bad = 0;
  __syncthreads();
  int found = 0;
  for(int i = threadIdx.x; i < 4096; i += 256){
    float v = bf2f(x[i]);
    if(!(fabsf(v) < 16.0f)) found = 1;   // catches big, inf, NaN
  }
  if(found) atomicOr(&bad, 1);
  __syncthreads();
  if(threadIdx.x == 0) mode[0] = bad ? 0 : 1;   // 1 = bf16 data, 0 = fp32 data
}

// ---------------- convert any input array to fp32 scratch --------------------
__global__ __launch_bounds__(256) void convK(const void* __restrict__ src, float* __restrict__ dst,
                                             int n, const int* __restrict__ mode){
  int m = mode[0];
  int i = blockIdx.x * 256 + threadIdx.x;
  if(i < n) dst[i] = m ? bf2f(((const u16*)src)[i]) : ((const float*)src)[i];
}

// ---------------- setup: P~ = (DT^2/c) * W^T W  and  Wt = W^T ----------------
__global__ __launch_bounds__(256) void setupA(const float* __restrict__ wb,
                                              float* __restrict__ P,
                                              float* __restrict__ Wt){
  __shared__ float W[U*U];
  const int l = blockIdx.x >> 3, rc = blockIdx.x & 7;
  const int t = threadIdx.x;
  const float* wl = wb + l*U*U;
  for(int i = t; i < (U*U)/4; i += 256) ((float4*)W)[i] = ((const float4*)wl)[i];
  __syncthreads();
  const int i0 = rc*16 + (t>>5)*2;
  const int j0 = (t&31)*4;
  float4 a0 = {0,0,0,0}, a1 = {0,0,0,0};
  for(int k=0;k<U;k++){
    float4 w4 = *((const float4*)&W[k*U + j0]);
    float x0 = W[k*U + i0], x1 = W[k*U + i0 + 1];
    a0.x += x0*w4.x; a0.y += x0*w4.y; a0.z += x0*w4.z; a0.w += x0*w4.w;
    a1.x += x1*w4.x; a1.y += x1*w4.y; a1.z += x1*w4.z; a1.w += x1*w4.w;
  }
  float4 p0, p1;
  p0.x = AFACT*a0.x; p0.y = AFACT*a0.y; p0.z = AFACT*a0.z; p0.w = AFACT*a0.w;
  p1.x = AFACT*a1.x; p1.y = AFACT*a1.y; p1.z = AFACT*a1.z; p1.w = AFACT*a1.w;
  *((float4*)&P[(l*U + i0    )*U + j0]) = p0;
  *((float4*)&P[(l*U + i0 + 1)*U + j0]) = p1;
  for(int kk = i0; kk <= i0+1; ++kk){
    float4 v;
    v.x = W[(j0+0)*U + kk]; v.y = W[(j0+1)*U + kk];
    v.z = W[(j0+2)*U + kk]; v.w = W[(j0+3)*U + kk];
    *((float4*)&Wt[(l*U + kk)*U + j0]) = v;
  }
}

// ---------------- setup: S = (1/c)(I - P~ + P~^2) ----------------------------
__global__ __launch_bounds__(256) void setupB(const float* __restrict__ P,
                                              float* __restrict__ S){
  __shared__ float Pr[16*U];
  const int l = blockIdx.x >> 3, rc = blockIdx.x & 7;
  const int t = threadIdx.x;
  const float* Pl = P + l*U*U;
  for(int i=t;i<(16*U)/4;i+=256) ((float4*)Pr)[i] = ((const float4*)(Pl + rc*16*U))[i];
  __syncthreads();
  const int il = (t>>5)*2;
  const int j0 = (t&31)*4;
  float4 a0={0,0,0,0}, a1={0,0,0,0};
  for(int k=0;k<U;k++){
    float4 p4 = *((const float4*)&Pl[k*U + j0]);
    float x0 = Pr[il*U + k], x1 = Pr[(il+1)*U + k];
    a0.x += x0*p4.x; a0.y += x0*p4.y; a0.z += x0*p4.z; a0.w += x0*p4.w;
    a1.x += x1*p4.x; a1.y += x1*p4.y; a1.z += x1*p4.z; a1.w += x1*p4.w;
  }
  const int gi = rc*16 + il;
  float4 pij0 = *((const float4*)&Pl[ gi   *U + j0]);
  float4 pij1 = *((const float4*)&Pl[(gi+1)*U + j0]);
  float4 s0, s1;
  s0.x = INVC*(((gi  ==j0+0)?1.0f:0.0f) - pij0.x + a0.x);
  s0.y = INVC*(((gi  ==j0+1)?1.0f:0.0f) - pij0.y + a0.y);
  s0.z = INVC*(((gi  ==j0+2)?1.0f:0.0f) - pij0.z + a0.z);
  s0.w = INVC*(((gi  ==j0+3)?1.0f:0.0f) - pij0.w + a0.w);
  s1.x = INVC*(((gi+1==j0+0)?1.0f:0.0f) - pij1.x + a1.x);
  s1.y = INVC*(((gi+1==j0+1)?1.0f:0.0f) - pij1.y + a1.y);
  s1.z = INVC*(((gi+1==j0+2)?1.0f:0.0f) - pij1.z + a1.z);
  s1.w = INVC*(((gi+1==j0+3)?1.0f:0.0f) - pij1.w + a1.w);
  *((float4*)&S[(l*U+gi  )*U + j0]) = s0;
  *((float4*)&S[(l*U+gi+1)*U + j0]) = s1;
}

// ---------------- matmul helper: (LDS row 128) x (global fp32 128x128) -------
__device__ __forceinline__ float4 mmF(const float* a, const float* __restrict__ Bp, int j0){
  float4 acc = {0,0,0,0};
  #pragma unroll 4
  for(int k=0;k<U;k+=4){
    float4 av = *((const float4*)(a + k));
    const float* bp = Bp + k*U + j0;
    float4 r0 = *((const float4*)bp);
    float4 r1 = *((const float4*)(bp + U));
    float4 r2 = *((const float4*)(bp + 2*U));
    float4 r3 = *((const float4*)(bp + 3*U));
    acc.x += av.x*r0.x + av.y*r1.x + av.z*r2.x + av.w*r3.x;
    acc.y += av.x*r0.y + av.y*r1.y + av.z*r2.y + av.w*r3.y;
    acc.z += av.x*r0.z + av.y*r1.z + av.z*r2.z + av.w*r3.z;
    acc.w += av.x*r0.w + av.y*r1.w + av.z*r2.w + av.w*r3.w;
  }
  return acc;
}

// ---------------- main: 8 batch rows per block through everything ------------
__global__ __launch_bounds__(256) void mainK(const void* __restrict__ xraw,
                                             const float* __restrict__ w_in,
                                             const float* __restrict__ b_in,
                                             const float* __restrict__ wb,
                                             const float* __restrict__ bb,
                                             const float* __restrict__ w_out,
                                             const float* __restrict__ b_out,
                                             const float* __restrict__ S,
                                             const float* __restrict__ Wt,
                                             float* __restrict__ zu,
                                             void* __restrict__ outraw,
                                             const int* __restrict__ modep){
  __shared__ float xs[8*784];
  __shared__ float zin[8*256];
  __shared__ float carry[8*256];
  __shared__ float ru[8*U];
  __shared__ float Gm[8*U];
  __shared__ float Yv[8*U];
  __shared__ float lg[8*16];

  const int t  = threadIdx.x;
  const int r0 = blockIdx.x * 8;
  const int r  = t >> 5;
  const int j0 = (t & 31) * 4;
  const int m  = modep[0];

  // ---- phase 1: stage x rows (dtype-branch), z_in = [x1, tanh(x1)] ----
  for(int rr=0; rr<8; ++rr){
    if(t < 196){
      int b = rr*784 + t*4;
      if(m){
        ushort4 h = ((const ushort4*)((const u16*)xraw + (size_t)(r0+rr)*784))[t];
        xs[b]=bf2f(h.x); xs[b+1]=bf2f(h.y); xs[b+2]=bf2f(h.z); xs[b+3]=bf2f(h.w);
      } else {
        float4 f = ((const float4*)((const float*)xraw + (size_t)(r0+rr)*784))[t];
        *((float4*)&xs[b]) = f;
      }
    }
  }
  __syncthreads();
  {
    float4 acc = {0,0,0,0};
    const float* w0 = w_in + (size_t)(j0+0)*784;
    const float* w1 = w_in + (size_t)(j0+1)*784;
    const float* w2 = w_in + (size_t)(j0+2)*784;
    const float* w3 = w_in + (size_t)(j0+3)*784;
    for(int d=0; d<784; d+=4){
      float4 xv = *((const float4*)&xs[r*784 + d]);
      float4 a0 = *((const float4*)(w0 + d));
      float4 a1 = *((const float4*)(w1 + d));
      float4 a2 = *((const float4*)(w2 + d));
      float4 a3 = *((const float4*)(w3 + d));
      acc.x += xv.x*a0.x + xv.y*a0.y + xv.z*a0.z + xv.w*a0.w;
      acc.y += xv.x*a1.x + xv.y*a1.y + xv.z*a1.z + xv.w*a1.w;
      acc.z += xv.x*a2.x + xv.y*a2.y + xv.z*a2.z + xv.w*a2.w;
      acc.w += xv.x*a3.x + xv.y*a3.y + xv.z*a3.z + xv.w*a3.w;
    }
    float v0 = acc.x + b_in[j0+0];
    float v1 = acc.y + b_in[j0+1];
    float v2 = acc.z + b_in[j0+2];
    float v3 = acc.w + b_in[j0+3];
    zin[r*256 + j0+0] = v0; zin[r*256 + 128 + j0+0] = tanhf(v0);
    zin[r*256 + j0+1] = v1; zin[r*256 + 128 + j0+1] = tanhf(v1);
    zin[r*256 + j0+2] = v2; zin[r*256 + 128 + j0+2] = tanhf(v2);
    zin[r*256 + j0+3] = v3; zin[r*256 + 128 + j0+3] = tanhf(v3);
  }
  __syncthreads();

  // ---- phase 2: 15 sweeps x 8 layers ----
  for(int s=0; s<NS; ++s){
    {
      ((float4*)carry)[t]       = ((const float4*)zin)[t];
      ((float4*)carry)[t + 256] = ((const float4*)zin)[t + 256];
      float4 z = *((const float4*)&zin[r*256 + j0]);
      float4 rv;
      rv.x = DTc*bb[j0+0] + z.x;
      rv.y = DTc*bb[j0+1] + z.y;
      rv.z = DTc*bb[j0+2] + z.z;
      rv.w = DTc*bb[j0+3] + z.w;
      *((float4*)&ru[r*U + j0]) = rv;
    }
    __syncthreads();
    for(int l=0; l<NL; ++l){
      // G = rhs_v + DT*(rhs_u @ W)
      {
        float4 acc = mmF(&ru[r*U], wb + (size_t)l*U*U, j0);
        float4 zo;
        if(s == 0) zo = *((const float4*)&zin[r*256 + j0]);
        else       zo = *((const float4*)&zu[((size_t)(l*BATCH + r0 + r))*U + j0]);
        float4 cv = *((const float4*)&carry[r*256 + 128 + j0]);
        float4 g;
        g.x = TENf*tanhf(zo.x) + cv.x + DTc*acc.x;
        g.y = TENf*tanhf(zo.y) + cv.y + DTc*acc.y;
        g.z = TENf*tanhf(zo.z) + cv.z + DTc*acc.z;
        g.w = TENf*tanhf(zo.w) + cv.w + DTc*acc.w;
        *((float4*)&Gm[r*U + j0]) = g;
      }
      __syncthreads();
      // y_v = G @ S
      {
        float4 acc = mmF(&Gm[r*U], S + (size_t)l*U*U, j0);
        *((float4*)&Yv[r*U + j0]) = acc;
        *((float4*)&carry[r*256 + 128 + j0]) = acc;
      }
      __syncthreads();
      // y_u = rhs_u - DT*(y_v @ W^T)
      {
        float4 acc = mmF(&Yv[r*U], Wt + (size_t)l*U*U, j0);
        float4 rr4 = *((const float4*)&ru[r*U + j0]);
        float4 yu;
        yu.x = rr4.x - DTc*acc.x;
        yu.y = rr4.y - DTc*acc.y;
        yu.z = rr4.z - DTc*acc.z;
        yu.w = rr4.w - DTc*acc.w;
        *((float4*)&carry[r*256 + j0]) = yu;
        *((float4*)&zu[((size_t)(l*BATCH + r0 + r))*U + j0]) = yu;
        if(l < NL-1){
          float4 rn;
          rn.x = DTc*bb[(l+1)*U + j0+0] + yu.x;
          rn.y = DTc*bb[(l+1)*U + j0+1] + yu.y;
          rn.z = DTc*bb[(l+1)*U + j0+2] + yu.z;
          rn.w = DTc*bb[(l+1)*U + j0+3] + yu.w;
          *((float4*)&ru[r*U + j0]) = rn;
        }
      }
      __syncthreads();
    }
  }

  // ---- epilogue: u_out = z_in_u + DT*b7 - DT*(v7 @ W7^T); logits; softmax ----
  {
    float4 acc = mmF(&carry[r*256 + 128], Wt + (size_t)(NL-1)*U*U, j0);
    float4 u;
    u.x = zin[r*256 + j0+0] + DTc*bb[(NL-1)*U + j0+0] - DTc*acc.x;
    u.y = zin[r*256 + j0+1] + DTc*bb[(NL-1)*U + j0+1] - DTc*acc.y;
    u.z = zin[r*256 + j0+2] + DTc*bb[(NL-1)*U + j0+2] - DTc*acc.z;
    u.w = zin[r*256 + j0+3] + DTc*bb[(NL-1)*U + j0+3] - DTc*acc.w;
    *((float4*)&Gm[r*U + j0]) = u;
  }
  __syncthreads();
  if(t < 128){
    int rr = t >> 4, o = t & 15;
    if(o < 10){
      float acc = b_out[o];
      const float* wo = w_out + o*U;
      for(int k=0;k<U;k++) acc += Gm[rr*U + k]*wo[k];
      lg[rr*16 + o] = acc;
    }
  }
  __syncthreads();
  if(t < 8){
    float mx = -1e30f;
    for(int o=0;o<10;o++) mx = fmaxf(mx, lg[t*16 + o]);
    float e[10]; float sum = 0.0f;
    for(int o=0;o<10;o++){ e[o] = __expf(lg[t*16 + o] - mx); sum += e[o]; }
    float inv = 1.0f / sum;
    for(int o=0;o<10;o++){
      float p = e[o]*inv;
      if(m) ((u16*)outraw)[(size_t)(r0 + t)*10 + o] = f2bf(p);
      else  ((float*)outraw)[(size_t)(r0 + t)*10 + o] = p;
    }
  }
}

extern "C" void kernel_launch(void* const* d_in, const int* in_sizes, int n_in,
                              void* d_out, int out_size, void* d_ws, size_t ws_size,
                              hipStream_t stream) {
  float* ws   = (float*)d_ws;
  int*   mode = (int*)ws;                    // [0]
  float* w_in_f  = ws + 16;                  // 100352
  float* b_in_f  = ws + 100368;              // 128
  float* wb_f    = ws + 100496;              // 131072
  float* bb_f    = ws + 231568;              // 1024
  float* w_out_f = ws + 232592;              // 1280
  float* b_out_f = ws + 233872;              // 16
  float* Sm      = ws + 233888;              // 131072
  float* Wt      = ws + 364960;              // 131072
  float* zu      = ws + 496032;              // 2097152 (8*2048*128)
  float* P       = zu;                       // alias: P dead before zu live

  detectK<<<1, 256, 0, stream>>>((const u16*)d_in[0], mode);
  convK<<<(100352+255)/256, 256, 0, stream>>>(d_in[1], w_in_f, 100352, mode);
  convK<<<1,              256, 0, stream>>>(d_in[2], b_in_f,  128,    mode);
  convK<<<(131072+255)/256, 256, 0, stream>>>(d_in[3], wb_f,  131072, mode);
  convK<<<4,              256, 0, stream>>>(d_in[4], bb_f,    1024,   mode);
  convK<<<5,              256, 0, stream>>>(d_in[5], w_out_f, 1280,   mode);
  convK<<<1,              256, 0, stream>>>(d_in[6], b_out_f, 10,     mode);

  setupA<<<64, 256, 0, stream>>>(wb_f, P, Wt);
  setupB<<<64, 256, 0, stream>>>(P, Sm);
  mainK<<<BATCH/8, 256, 0, stream>>>(d_in[0], w_in_f, b_in_f, wb_f, bb_f,
                                     w_out_f, b_out_f, Sm, Wt, zu, d_out, mode);
}

// Round 3
// 434.422 us; speedup vs baseline: 3.6906x; 3.6906x over previous
//
#include <hip/hip_runtime.h>
#include <hip/hip_bf16.h>

#define U 128
#define BATCH 2048
#define NL 8
#define NS 15
#define DTc 0.1f
#define TENf 10.0f                 /* DT/EPS */
#define INVC (1.0f/11.0f)          /* 1/(1+DT/EPS) */
#define AFACT (0.01f/11.0f)        /* DT^2 / c */

typedef unsigned short u16;
typedef __attribute__((ext_vector_type(8))) short bf16x8;
typedef __attribute__((ext_vector_type(4))) float f32x4;
#define MFMA16(a,b,c) __builtin_amdgcn_mfma_f32_16x16x32_bf16(a,b,c,0,0,0)

__device__ __forceinline__ float bf2f(u16 h){ return __uint_as_float(((unsigned int)h)<<16); }
__device__ __forceinline__ u16 f2bf(float f){
  unsigned int u = __float_as_uint(f);
  u += 0x7FFFu + ((u >> 16) & 1u);
  return (u16)(u >> 16);
}
__device__ __forceinline__ float fast_tanh(float x){
  float e = __expf(2.0f*x);
  return 1.0f - __fdividef(2.0f, e + 1.0f);
}

// ---------------- dtype detect ----------------------------------------------
__global__ __launch_bounds__(256) void detectK(const u16* __restrict__ x, int* __restrict__ mode){
  __shared__ int bad;
  if(threadIdx.x == 0) bad = 0;
  __syncthreads();
  int found = 0;
  for(int i = threadIdx.x; i < 4096; i += 256){
    float v = bf2f(x[i]);
    if(!(fabsf(v) < 16.0f)) found = 1;
  }
  if(found) atomicOr(&bad, 1);
  __syncthreads();
  if(threadIdx.x == 0) mode[0] = bad ? 0 : 1;   // 1 = bf16 data, 0 = fp32 data
}

// ---------------- convert all params ----------------------------------------
__global__ __launch_bounds__(256) void convAllK(const void* __restrict__ w_in, const void* __restrict__ wb,
                                                const void* __restrict__ b_in, const void* __restrict__ bb,
                                                const void* __restrict__ w_out, const void* __restrict__ b_out,
                                                u16* __restrict__ winb, float* __restrict__ wbf, u16* __restrict__ wbb,
                                                float* __restrict__ b_in_f, float* __restrict__ bbf,
                                                float* __restrict__ w_out_f, float* __restrict__ b_out_f,
                                                const int* __restrict__ modep){
  const int m = modep[0];
  int i = blockIdx.x*256 + threadIdx.x;
  if(i < 100352){
    winb[i] = m ? ((const u16*)w_in)[i] : f2bf(((const float*)w_in)[i]);
  } else if(i < 231424){
    int j = i - 100352;
    float v = m ? bf2f(((const u16*)wb)[j]) : ((const float*)wb)[j];
    wbf[j] = v;
    wbb[j] = m ? ((const u16*)wb)[j] : f2bf(v);
  } else if(i < 231552){
    int j = i - 231424; b_in_f[j]  = m ? bf2f(((const u16*)b_in)[j])  : ((const float*)b_in)[j];
  } else if(i < 232576){
    int j = i - 231552; bbf[j]     = m ? bf2f(((const u16*)bb)[j])    : ((const float*)bb)[j];
  } else if(i < 233856){
    int j = i - 232576; w_out_f[j] = m ? bf2f(((const u16*)w_out)[j]) : ((const float*)w_out)[j];
  } else if(i < 233866){
    int j = i - 233856; b_out_f[j] = m ? bf2f(((const u16*)b_out)[j]) : ((const float*)b_out)[j];
  }
}

// ---------------- setup: P = (DT^2/c) W^T W (fp32), wtb = W^T (bf16) --------
__global__ __launch_bounds__(256) void setupT(const float* __restrict__ wbf,
                                              float* __restrict__ P,
                                              u16* __restrict__ wtb){
  __shared__ float W[U*U];
  const int l = blockIdx.x >> 3, rc = blockIdx.x & 7;
  const int t = threadIdx.x;
  const float* wl = wbf + l*U*U;
  for(int i = t; i < (U*U)/4; i += 256) ((float4*)W)[i] = ((const float4*)wl)[i];
  __syncthreads();
  const int i0 = rc*16 + (t>>5)*2;
  const int j0 = (t&31)*4;
  float4 a0 = {0,0,0,0}, a1 = {0,0,0,0};
  for(int k=0;k<U;k++){
    float4 w4 = *((const float4*)&W[k*U + j0]);
    float x0 = W[k*U + i0], x1 = W[k*U + i0 + 1];
    a0.x += x0*w4.x; a0.y += x0*w4.y; a0.z += x0*w4.z; a0.w += x0*w4.w;
    a1.x += x1*w4.x; a1.y += x1*w4.y; a1.z += x1*w4.z; a1.w += x1*w4.w;
  }
  *((float4*)&P[(l*U + i0    )*U + j0]) = make_float4(AFACT*a0.x, AFACT*a0.y, AFACT*a0.z, AFACT*a0.w);
  *((float4*)&P[(l*U + i0 + 1)*U + j0]) = make_float4(AFACT*a1.x, AFACT*a1.y, AFACT*a1.z, AFACT*a1.w);
  for(int kk = i0; kk <= i0+1; ++kk){
    // wtb[n][k] = W[k][n]  -> here row kk of wtb gets W[j][kk]
    wtb[(l*U + kk)*U + j0+0] = f2bf(W[(j0+0)*U + kk]);
    wtb[(l*U + kk)*U + j0+1] = f2bf(W[(j0+1)*U + kk]);
    wtb[(l*U + kk)*U + j0+2] = f2bf(W[(j0+2)*U + kk]);
    wtb[(l*U + kk)*U + j0+3] = f2bf(W[(j0+3)*U + kk]);
  }
}

// ---------------- setup: S = (1/c)(I - P + P^2) -> bf16 ----------------------
__global__ __launch_bounds__(256) void setupS(const float* __restrict__ P,
                                              u16* __restrict__ sb){
  __shared__ float Pr[16*U];
  const int l = blockIdx.x >> 3, rc = blockIdx.x & 7;
  const int t = threadIdx.x;
  const float* Pl = P + l*U*U;
  for(int i=t;i<(16*U)/4;i+=256) ((float4*)Pr)[i] = ((const float4*)(Pl + rc*16*U))[i];
  __syncthreads();
  const int il = (t>>5)*2;
  const int j0 = (t&31)*4;
  float4 a0={0,0,0,0}, a1={0,0,0,0};
  for(int k=0;k<U;k++){
    float4 p4 = *((const float4*)&Pl[k*U + j0]);
    float x0 = Pr[il*U + k], x1 = Pr[(il+1)*U + k];
    a0.x += x0*p4.x; a0.y += x0*p4.y; a0.z += x0*p4.z; a0.w += x0*p4.w;
    a1.x += x1*p4.x; a1.y += x1*p4.y; a1.z += x1*p4.z; a1.w += x1*p4.w;
  }
  const int gi = rc*16 + il;
  float4 pij0 = *((const float4*)&Pl[ gi   *U + j0]);
  float4 pij1 = *((const float4*)&Pl[(gi+1)*U + j0]);
  sb[(l*U+gi  )*U + j0+0] = f2bf(INVC*(((gi  ==j0+0)?1.0f:0.0f) - pij0.x + a0.x));
  sb[(l*U+gi  )*U + j0+1] = f2bf(INVC*(((gi  ==j0+1)?1.0f:0.0f) - pij0.y + a0.y));
  sb[(l*U+gi  )*U + j0+2] = f2bf(INVC*(((gi  ==j0+2)?1.0f:0.0f) - pij0.z + a0.z));
  sb[(l*U+gi  )*U + j0+3] = f2bf(INVC*(((gi  ==j0+3)?1.0f:0.0f) - pij0.w + a0.w));
  sb[(l*U+gi+1)*U + j0+0] = f2bf(INVC*(((gi+1==j0+0)?1.0f:0.0f) - pij1.x + a1.x));
  sb[(l*U+gi+1)*U + j0+1] = f2bf(INVC*(((gi+1==j0+1)?1.0f:0.0f) - pij1.y + a1.y));
  sb[(l*U+gi+1)*U + j0+2] = f2bf(INVC*(((gi+1==j0+2)?1.0f:0.0f) - pij1.z + a1.z));
  sb[(l*U+gi+1)*U + j0+3] = f2bf(INVC*(((gi+1==j0+3)?1.0f:0.0f) - pij1.w + a1.w));
}

// ---------------- main: 16 rows/block, MFMA 16x16x32 bf16 --------------------
// layouts (measured, learn_hip m89/m120): A[m=lane&15][k=quad*8+j],
// B[k][n=lane&15] with k=quad*8+j (contiguous-in-k arrays), C/D col=lane&15,
// row=quad*4+reg.
__global__ __launch_bounds__(256) void mainK(const void* __restrict__ xraw,
                                             const u16* __restrict__ winb,
                                             const float* __restrict__ b_in_f,
                                             const u16* __restrict__ wtb,   // [l][n][k] = W[k][n]
                                             const u16* __restrict__ sb,    // [l][n][k] = S (symmetric)
                                             const u16* __restrict__ wbb,   // [l][n][k] = W[n][k]
                                             const float* __restrict__ bbf,
                                             const float* __restrict__ w_out_f,
                                             const float* __restrict__ b_out_f,
                                             void* __restrict__ outraw,
                                             const int* __restrict__ modep){
  __shared__ u16  xs[16*800];       // 25.6 KB, cols 784..799 zeroed
  __shared__ u16  Ab[2][16*136];    // ping-pong A-operand buffers (pad +8)
  __shared__ float zin[16*264];     // z_in u|v halves, fp32 (pad stride 264)
  __shared__ float bbL[NL*U];
  __shared__ float lg[16*12];

  const int t    = threadIdx.x;
  const int lane = t & 63;
  const int wid  = t >> 6;           // 4 waves, each owns 32 cols
  const int ln   = lane & 15;
  const int lq   = lane >> 4;
  const int nbase = wid * 32;
  const int n0 = nbase + ln;
  const int n1 = nbase + 16 + ln;
  const int r0 = blockIdx.x * 16;
  const int m  = modep[0];

  // ---- stage bb, zero x pad ----
  for(int i=t;i<NL*U;i+=256) bbL[i] = bbf[i];
  { int row = t >> 4, c = 784 + (t & 15); xs[row*800 + c] = 0; }
  // ---- stage x rows (16 x 784) as bf16 ----
  for(int idx = t; idx < 16*196; idx += 256){
    int row = idx / 196, c4 = idx - row*196;
    ushort4 hv;
    if(m){
      hv = ((const ushort4*)xraw)[((size_t)(r0+row)*784)/4 + c4];
    } else {
      float4 f = ((const float4*)xraw)[(size_t)(r0+row)*196 + c4];
      hv.x = f2bf(f.x); hv.y = f2bf(f.y); hv.z = f2bf(f.z); hv.w = f2bf(f.w);
    }
    *((ushort4*)&xs[row*800 + c4*4]) = hv;
  }
  __syncthreads();

  // ---- phase 1: z1 = x @ w_in^T + b_in (MFMA over K=784) ----
  f32x4 acc0 = {0,0,0,0}, acc1 = {0,0,0,0};
  for(int kt=0; kt<25; ++kt){
    int k0 = kt*32 + lq*8;
    bf16x8 av = *(const bf16x8*)&xs[ln*800 + k0];
    bf16x8 b0 = {0,0,0,0,0,0,0,0}, b1 = {0,0,0,0,0,0,0,0};
    if(k0 < 784){
      b0 = *(const bf16x8*)&winb[(size_t)n0*784 + k0];
      b1 = *(const bf16x8*)&winb[(size_t)n1*784 + k0];
    }
    acc0 = MFMA16(av, b0, acc0);
    acc1 = MFMA16(av, b1, acc1);
  }
  unsigned zhp[NL][4];               // packed bf16 z-history (lo=n0 val, hi=n1 val)
  #pragma unroll
  for(int reg=0; reg<4; ++reg){
    int row = lq*4 + reg;
    float v0 = acc0[reg] + b_in_f[n0];
    float v1 = acc1[reg] + b_in_f[n1];
    zin[row*264 + n0] = v0;  zin[row*264 + 128 + n0] = fast_tanh(v0);
    zin[row*264 + n1] = v1;  zin[row*264 + 128 + n1] = fast_tanh(v1);
    unsigned pk = ((unsigned)f2bf(v1) << 16) | f2bf(v0);
    #pragma unroll
    for(int l=0;l<NL;l++) zhp[l][reg] = pk;
  }
  __syncthreads();

  // ---- phase 2: 15 sweeps x 8 layers, ping-pong LDS A-buffers ----
  float ruC0[4], ruC1[4], cv0[4], cv1[4];
  for(int s=0; s<NS; ++s){
    #pragma unroll
    for(int reg=0; reg<4; ++reg){
      int row = lq*4 + reg;
      float zu0 = zin[row*264 + n0], zu1 = zin[row*264 + n1];
      float rv0 = zu0 + DTc*bbL[n0];
      float rv1 = zu1 + DTc*bbL[n1];
      ruC0[reg] = rv0; ruC1[reg] = rv1;
      cv0[reg] = zin[row*264 + 128 + n0];
      cv1[reg] = zin[row*264 + 128 + n1];
      Ab[0][row*136 + n0] = f2bf(rv0);
      Ab[0][row*136 + n1] = f2bf(rv1);
    }
    __syncthreads();
    int cur = 0;
    for(int l=0; l<NL; ++l){
      const u16* Wt_l = wtb + l*U*U;
      const u16* S_l  = sb  + l*U*U;
      const u16* W2_l = wbb + l*U*U;
      // prefetch B-frags for G and Yv matmuls (latency cover)
      bf16x8 bG0[4], bG1[4], bS0[4], bS1[4];
      #pragma unroll
      for(int kt=0; kt<4; ++kt){
        int k0 = kt*32 + lq*8;
        bG0[kt] = *(const bf16x8*)&Wt_l[n0*U + k0];
        bG1[kt] = *(const bf16x8*)&Wt_l[n1*U + k0];
        bS0[kt] = *(const bf16x8*)&S_l [n0*U + k0];
        bS1[kt] = *(const bf16x8*)&S_l [n1*U + k0];
      }
      // --- G = TEN*tanh(z_prev) + carry_v + DT*(r_u @ W) ---
      bf16x8 aF[4];
      #pragma unroll
      for(int kt=0; kt<4; ++kt) aF[kt] = *(const bf16x8*)&Ab[cur][ln*136 + kt*32 + lq*8];
      f32x4 g0 = {0,0,0,0}, g1 = {0,0,0,0};
      #pragma unroll
      for(int kt=0; kt<4; ++kt){ g0 = MFMA16(aF[kt], bG0[kt], g0); g1 = MFMA16(aF[kt], bG1[kt], g1); }
      // prefetch Yu B-frags while G epilogue runs
      bf16x8 bU0[4], bU1[4];
      #pragma unroll
      for(int kt=0; kt<4; ++kt){
        int k0 = kt*32 + lq*8;
        bU0[kt] = *(const bf16x8*)&W2_l[n0*U + k0];
        bU1[kt] = *(const bf16x8*)&W2_l[n1*U + k0];
      }
      #pragma unroll
      for(int reg=0; reg<4; ++reg){
        int row = lq*4 + reg;
        float zo0 = bf2f((u16)(zhp[l][reg] & 0xffff));
        float zo1 = bf2f((u16)(zhp[l][reg] >> 16));
        float G0 = TENf*fast_tanh(zo0) + cv0[reg] + DTc*g0[reg];
        float G1 = TENf*fast_tanh(zo1) + cv1[reg] + DTc*g1[reg];
        Ab[1-cur][row*136 + n0] = f2bf(G0);
        Ab[1-cur][row*136 + n1] = f2bf(G1);
      }
      __syncthreads();
      // --- y_v = G @ S ---
      #pragma unroll
      for(int kt=0; kt<4; ++kt) aF[kt] = *(const bf16x8*)&Ab[1-cur][ln*136 + kt*32 + lq*8];
      f32x4 v0 = {0,0,0,0}, v1 = {0,0,0,0};
      #pragma unroll
      for(int kt=0; kt<4; ++kt){ v0 = MFMA16(aF[kt], bS0[kt], v0); v1 = MFMA16(aF[kt], bS1[kt], v1); }
      #pragma unroll
      for(int reg=0; reg<4; ++reg){
        int row = lq*4 + reg;
        cv0[reg] = v0[reg]; cv1[reg] = v1[reg];
        Ab[cur][row*136 + n0] = f2bf(v0[reg]);
        Ab[cur][row*136 + n1] = f2bf(v1[reg]);
      }
      __syncthreads();
      // --- y_u = r_u - DT*(y_v @ W^T) ---
      #pragma unroll
      for(int kt=0; kt<4; ++kt) aF[kt] = *(const bf16x8*)&Ab[cur][ln*136 + kt*32 + lq*8];
      f32x4 u0 = {0,0,0,0}, u1 = {0,0,0,0};
      #pragma unroll
      for(int kt=0; kt<4; ++kt){ u0 = MFMA16(aF[kt], bU0[kt], u0); u1 = MFMA16(aF[kt], bU1[kt], u1); }
      #pragma unroll
      for(int reg=0; reg<4; ++reg){
        int row = lq*4 + reg;
        float yu0 = ruC0[reg] - DTc*u0[reg];
        float yu1 = ruC1[reg] - DTc*u1[reg];
        zhp[l][reg] = ((unsigned)f2bf(yu1) << 16) | f2bf(yu0);
        if(l < NL-1){
          float rn0 = yu0 + DTc*bbL[(l+1)*U + n0];
          float rn1 = yu1 + DTc*bbL[(l+1)*U + n1];
          ruC0[reg] = rn0; ruC1[reg] = rn1;
          Ab[1-cur][row*136 + n0] = f2bf(rn0);
          Ab[1-cur][row*136 + n1] = f2bf(rn1);
        } else if(s == NS-1){
          // fused final epilogue: u_out = z_in_u + DT*b7 - DT*(y_v7 @ W7^T)
          float uo0 = zin[row*264 + n0] + DTc*bbL[(NL-1)*U + n0] - DTc*u0[reg];
          float uo1 = zin[row*264 + n1] + DTc*bbL[(NL-1)*U + n1] - DTc*u1[reg];
          zin[row*264 + n0] = uo0;
          zin[row*264 + n1] = uo1;
        }
      }
      __syncthreads();
      cur ^= 1;
    }
  }

  // ---- logits + softmax ----
  if(t < 160){
    int mm = t / 10, o = t - mm*10;
    float a = b_out_f[o];
    const float* wo = w_out_f + o*U;
    for(int k=0;k<U;k++) a += zin[mm*264 + k] * wo[k];
    lg[mm*12 + o] = a;
  }
  __syncthreads();
  if(t < 16){
    float mx = -1e30f;
    for(int o=0;o<10;o++) mx = fmaxf(mx, lg[t*12 + o]);
    float e[10]; float sum = 0.0f;
    for(int o=0;o<10;o++){ e[o] = __expf(lg[t*12 + o] - mx); sum += e[o]; }
    float inv = 1.0f / sum;
    for(int o=0;o<10;o++){
      float p = e[o]*inv;
      if(m) ((u16*)outraw)[(size_t)(r0 + t)*10 + o] = f2bf(p);
      else  ((float*)outraw)[(size_t)(r0 + t)*10 + o] = p;
    }
  }
}

extern "C" void kernel_launch(void* const* d_in, const int* in_sizes, int n_in,
                              void* d_out, int out_size, void* d_ws, size_t ws_size,
                              hipStream_t stream) {
  float* ws = (float*)d_ws;
  int*   mode    = (int*)ws;             // +0   (16 floats reserved)
  u16*   winb    = (u16*)(ws + 16);      // 100352 u16 -> 50176 f
  float* wbf     = ws + 50192;           // 131072 f
  u16*   wbb     = (u16*)(ws + 181264);  // 131072 u16 -> 65536 f
  u16*   wtb     = (u16*)(ws + 246800);  // 65536 f
  u16*   sbm     = (u16*)(ws + 312336);  // 65536 f
  float* P       = ws + 377872;          // 131072 f
  float* b_in_f  = ws + 508944;          // 128
  float* bbf     = ws + 509072;          // 1024
  float* w_out_f = ws + 510096;          // 1280
  float* b_out_f = ws + 511376;          // 16

  detectK<<<1, 256, 0, stream>>>((const u16*)d_in[0], mode);
  convAllK<<<914, 256, 0, stream>>>(d_in[1], d_in[3], d_in[2], d_in[4], d_in[5], d_in[6],
                                    winb, wbf, wbb, b_in_f, bbf, w_out_f, b_out_f, mode);
  setupT<<<64, 256, 0, stream>>>(wbf, P, wtb);
  setupS<<<64, 256, 0, stream>>>(P, sbm);
  mainK<<<BATCH/16, 256, 0, stream>>>(d_in[0], winb, b_in_f, wtb, sbm, wbb,
                                      bbf, w_out_f, b_out_f, d_out, mode);
}